// Round 9
// baseline (224.413 us; speedup 1.0000x reference)
//
#include <hip/hip_runtime.h>
#include <hip/hip_bf16.h>

// Conv2d 3x3 pad=1 stride=1, B=32, 256->256, 56x56, fp32 in/out.
// Implicit GEMM, m201-protocol port: 256co x 256px block, 8 waves (wave tile
// 128x64), BK=32, 16x16x32 MFMA. A (weights) fragment-packed in registers
// (L2-resident, 2-phase prefetch); B in LDS ring-4 (4 x 16KB). 4 fine phases
// per 2-K-tile iteration, each {ds_read || stage || A-load} -> barrier ->
// lgkm0 -> setprio+16 MFMA -> barrier; vmcnt(12) ONLY at phases 2,4
// (counted, ~2-phase slack, never drains). Proven 64B-row swizzle (0 confl).

#define BB    32
#define CINC  256
#define COUTC 256
#define HH    56
#define WW    56
#define HP    58
#define WP    58
#define PIX_PER_IMG 3136
#define NPIX  100352
#define KTOT  2304
#define NKT   72                      // K-tiles of 32

#define XT_BYTES ((size_t)BB*HP*WP*CINC*2)
#define AWR_FRAGS (72*16*64)          // (t, mb, lane) 16B frags
#define AWR_BYTES ((size_t)AWR_FRAGS*16)

#define BUF_SZ 16384                  // B(kt): 256 rows x 64B
#define NT    392

using frag_t = __attribute__((ext_vector_type(8))) short;   // 8 bf16
using f32x4  = __attribute__((ext_vector_type(4))) float;

__device__ __forceinline__ void gload_lds16(const void* gsrc, void* ldst) {
  __builtin_amdgcn_global_load_lds(
      (const __attribute__((address_space(1))) unsigned*)gsrc,
      (__attribute__((address_space(3))) unsigned*)ldst, 16, 0, 0);
}

// ---------- pre-pass 1: NCHW fp32 -> padded channels-last bf16 Xt[b][58][58][256]
__global__ void xpose_kernel(const float* __restrict__ inp,
                             __hip_bfloat16* __restrict__ xt) {
  int bid = blockIdx.x;
  int hp = bid % HP;
  int t  = bid / HP;
  int cb = t % 4;
  int b  = t / 4;
  __shared__ __hip_bfloat16 tile[64 * 60];
  int tid = threadIdx.x;
  for (int i = tid; i < 64 * 60; i += 256) tile[i] = __float2bfloat16(0.f);
  __syncthreads();
  int h = hp - 1;
  if (h >= 0 && h < HH) {
    const float* src = inp + ((size_t)(b * CINC + cb * 64) * HH + h) * WW;
    for (int i = tid; i < 64 * WW; i += 256) {
      int ci = i / WW, w = i - ci * WW;
      tile[ci * 60 + (w + 1)] = __float2bfloat16(src[(size_t)ci * HH * WW + w]);
    }
  }
  __syncthreads();
  __hip_bfloat16* dst = xt + ((size_t)(b * HP + hp) * WP) * CINC + cb * 64;
  for (int i = tid; i < WP * 64; i += 256) {
    int wp = i >> 6, ci = i & 63;
    dst[(size_t)wp * CINC + ci] = tile[ci * 60 + wp];
  }
}

// ---------- pre-pass 2: OIHW fp32 -> fragment-ordered Awr[t][mb][lane] (16B)
// lane l of frag (t, mb) holds A[co = mb*16 + (l&15)][k = t*32 + (l>>4)*8 + j]
__global__ void wprep_pack(const float* __restrict__ k4,
                           frag_t* __restrict__ awr) {
  int i = blockIdx.x * 256 + threadIdx.x;   // (t*16 + mb)*64 + lane
  if (i >= AWR_FRAGS) return;
  int lane = i & 63;
  int mb   = (i >> 6) & 15;
  int t    = i >> 10;
  int co   = mb * 16 + (lane & 15);
  int kb   = t * 32 + (lane >> 4) * 8;
  frag_t v;
#pragma unroll
  for (int j = 0; j < 8; ++j) {
    int k = kb + j;
    int tap = k >> 8;
    int ci  = k & 255;
    __hip_bfloat16 h = __float2bfloat16(k4[(co * CINC + ci) * 9 + tap]);
    v[j] = *reinterpret_cast<short*>(&h);
  }
  awr[i] = v;
}

// ---------- main kernel
__global__ __launch_bounds__(512, 1) void conv_ph(
    const __hip_bfloat16* __restrict__ xt,
    const frag_t* __restrict__ awr,
    const float* __restrict__ bias,
    float* __restrict__ out) {
  __shared__ alignas(16) char lds[4 * BUF_SZ];   // 64 KiB ring-4 (B only)

  const int tid  = threadIdx.x;
  const int lane = tid & 63;
  const int wid  = tid >> 6;          // 0..7
  const int wm   = wid >> 2;          // co half: rows wm*128..+127
  const int wn   = wid & 3;           // px quarter: cols wn*64..+63
  const int fr   = lane & 15;
  const int g    = lane >> 4;         // 0..3 k-chunk

  const int bid   = blockIdx.x;
  const int ptile = (bid & 7) * 49 + (bid >> 3);   // 392 = 8*49, bijective

  const char* xt_b = (const char*)xt;

  // B staging: 1KB gload = 16 rows x 64B. lane l -> row l>>2, phys chunk l&3.
  // swizzle: LDS[row][phys] holds logical chunk (phys - ((row>>1)&3)) & 3.
  const int lr  = lane >> 2;
  const int sc  = ((((lane & 3) - ((lane >> 3) & 3)) & 3) << 4);

  auto mkB = [&](int h) -> const char* {
    int px = ptile * 256 + h * 128 + wid * 16 + lr;
    int b  = px / PIX_PER_IMG;
    int hw = px - b * PIX_PER_IMG;
    int hh = hw / WW, w = hw - hh * WW;
    return xt_b + (size_t)((b * HP + hh) * WP + w) * (CINC * 2) + sc;
  };
  const char* pB0 = mkB(0);
  const char* pB1 = mkB(1);

  // stage ONE 8KB half (1 gload/wave): B(kt) half H -> buf WB
#define STG1(KT, WB, H) {                                                  \
    int _kt = (KT) <= 71 ? (KT) : 71;                                      \
    int _tap = _kt >> 3; int _rr = _tap / 3, _ss = _tap - _rr * 3;         \
    size_t _bo = (size_t)(_rr * WP + _ss) * (CINC * 2)                     \
               + (size_t)(_kt & 7) * 64;                                   \
    gload_lds16(((H) ? pB1 : pB0) + _bo,                                   \
                lds + (WB) * BUF_SZ + (H) * 8192 + wid * 1024); }

  // A frag loads: frag index (t*16 + wm*8 + qm*4 + m)*64 + lane
  const frag_t* abase = awr + (size_t)(wm * 8) * 64 + lane;

#define ALOAD4(T1, QM, DST) {                                              \
    int _t = (T1) <= 71 ? (T1) : 71;                                       \
    const frag_t* _p = abase + ((size_t)_t * 16 + (QM) * 4) * 64;          \
    _Pragma("unroll") for (int m = 0; m < 4; ++m)                          \
      (DST)[m] = _p[m * 64]; }

  // B frag reads: row = wn*64 + n*16 + fr -> phys chunk (g + (fr>>1)) & 3
  const int ckr   = (((g + (fr >> 1)) & 3) << 4);
  const int broff = (wn * 64 + fr) * 64 + ckr;

  frag_t fa0[8], fa1[8], fbA[4], fbB[4];
  f32x4 acc[8][4] = {};

#define RSL(RB, FB) {                                                      \
    const char* _b = lds + (RB) * BUF_SZ;                                  \
    _Pragma("unroll") for (int n = 0; n < 4; ++n)                          \
      (FB)[n] = *(const frag_t*)(_b + broff + n * 1024); }

#define MFP(QM, FA, FB) {                                                  \
    __builtin_amdgcn_s_setprio(1);                                        \
    _Pragma("unroll") for (int m = 0; m < 4; ++m)                          \
    _Pragma("unroll") for (int n = 0; n < 4; ++n)                          \
      acc[(QM) * 4 + m][n] = __builtin_amdgcn_mfma_f32_16x16x32_bf16(      \
          (FA)[(QM) * 4 + m], (FB)[n], acc[(QM) * 4 + m][n], 0, 0, 0);     \
    __builtin_amdgcn_s_setprio(0); }

#define BAR()  __builtin_amdgcn_s_barrier()
#define LGKM0() { asm volatile("s_waitcnt lgkmcnt(0)" ::: "memory");       \
                  __builtin_amdgcn_sched_barrier(0); }
#define VM12() { asm volatile("s_waitcnt vmcnt(12)" ::: "memory");         \
                 __builtin_amdgcn_sched_barrier(0); }

  // One iteration = K-tiles (KT0, KT0+1) read from (RB0, RB1);
  // stages B(KT0+2)->WB0 (ph1,2), B(KT0+3)->WB1 (ph3,4);
  // A prefetch: ph1,2 -> A(KT0+1) into FA1; ph3,4 -> A(KT0+2) into FA0.
#define ITER(KT0, RB0, RB1, WB0, WB1) {                                    \
    /* phase 1: quadrant (kt0, qm0) */                                     \
    RSL(RB0, fbA);                                                         \
    STG1((KT0) + 2, WB0, 0);                                               \
    ALOAD4((KT0) + 1, 0, fa1);                                             \
    BAR(); LGKM0();                                                        \
    MFP(0, fa0, fbA);                                                      \
    BAR();                                                                 \
    /* phase 2: (kt0, qm1); counted wait */                                \
    STG1((KT0) + 2, WB0, 1);                                               \
    ALOAD4((KT0) + 1, 1, fa1 + 4);                                         \
    VM12();                                                                \
    BAR(); LGKM0();                                                        \
    MFP(1, fa0, fbA);                                                      \
    BAR();                                                                 \
    /* phase 3: (kt1, qm0) */                                              \
    RSL(RB1, fbB);                                                         \
    STG1((KT0) + 3, WB1, 0);                                               \
    ALOAD4((KT0) + 2, 0, fa0);                                             \
    BAR(); LGKM0();                                                        \
    MFP(0, fa1, fbB);                                                      \
    BAR();                                                                 \
    /* phase 4: (kt1, qm1); counted wait */                                \
    STG1((KT0) + 3, WB1, 1);                                               \
    ALOAD4((KT0) + 2, 1, fa0 + 4);                                         \
    VM12();                                                                \
    BAR(); LGKM0();                                                        \
    MFP(1, fa1, fbB);                                                      \
    BAR(); }

  // ---- prologue: B(0)->buf0, B(1)->buf1, A(0)->fa0; full drain once
  STG1(0, 0, 0); STG1(0, 0, 1);
  STG1(1, 1, 0); STG1(1, 1, 1);
  ALOAD4(0, 0, fa0);
  ALOAD4(0, 1, fa0 + 4);
  asm volatile("s_waitcnt vmcnt(0)" ::: "memory");
  BAR();
  __builtin_amdgcn_sched_barrier(0);

  // ---- 18 bodies x 2 iterations (ring parity static)
  for (int b = 0; b < 18; ++b) {
    int kt0 = b * 4;
    ITER(kt0,     0, 1, 2, 3);
    ITER(kt0 + 2, 2, 3, 0, 1);
  }

  // ---- epilogue: D layout col=lane&15 (px), row=(lane>>4)*4+reg (co)
  int pb[4], phw[4];
#pragma unroll
  for (int n = 0; n < 4; ++n) {
    int pxg = ptile * 256 + wn * 64 + n * 16 + fr;
    pb[n]  = pxg / PIX_PER_IMG;
    phw[n] = pxg - pb[n] * PIX_PER_IMG;
  }
#pragma unroll
  for (int m = 0; m < 8; ++m) {
#pragma unroll
    for (int rg = 0; rg < 4; ++rg) {
      int co = wm * 128 + m * 16 + g * 4 + rg;
      float bv = bias[co];
#pragma unroll
      for (int n = 0; n < 4; ++n)
        out[((size_t)pb[n] * COUTC + co) * PIX_PER_IMG + phw[n]] =
            acc[m][n][rg] + bv;
    }
  }
}

// ---------- correctness fallback if workspace is too small
__global__ void conv_direct(const float* __restrict__ inp,
                            const float* __restrict__ kern,
                            const float* __restrict__ bias,
                            float* __restrict__ out) {
  int idx = blockIdx.x * 256 + threadIdx.x;
  if (idx >= BB * COUTC * PIX_PER_IMG) return;
  int w = idx % WW;
  int t = idx / WW;
  int h = t % HH; t /= HH;
  int co = t % COUTC;
  int b  = t / COUTC;
  float acc = bias[co];
  for (int ci = 0; ci < CINC; ++ci)
    for (int r = 0; r < 3; ++r) {
      int hh = h + r - 1;
      if (hh < 0 || hh >= HH) continue;
      for (int s = 0; s < 3; ++s) {
        int ww2 = w + s - 1;
        if (ww2 < 0 || ww2 >= WW) continue;
        acc += inp[((size_t)(b * CINC + ci) * HH + hh) * WW + ww2] *
               kern[(co * CINC + ci) * 9 + r * 3 + s];
      }
    }
  out[idx] = acc;
}

extern "C" void kernel_launch(void* const* d_in, const int* in_sizes, int n_in,
                              void* d_out, int out_size, void* d_ws, size_t ws_size,
                              hipStream_t stream) {
  const float* inp  = (const float*)d_in[0];
  const float* kern = (const float*)d_in[1];
  const float* bias = (const float*)d_in[2];
  float* out = (float*)d_out;

  size_t need = XT_BYTES + AWR_BYTES;
  if (ws_size < need) {
    int tot = BB * COUTC * PIX_PER_IMG;
    conv_direct<<<(tot + 255) / 256, 256, 0, stream>>>(inp, kern, bias, out);
    return;
  }

  __hip_bfloat16* xt = (__hip_bfloat16*)d_ws;
  frag_t* awr = (frag_t*)((char*)d_ws + XT_BYTES);

  xpose_kernel<<<BB * 4 * HP, 256, 0, stream>>>(inp, xt);
  wprep_pack<<<(AWR_FRAGS + 255) / 256, 256, 0, stream>>>(kern, awr);
  conv_ph<<<NT, 512, 0, stream>>>(xt, awr, bias, out);
}